// Round 1
// baseline (102.760 us; speedup 1.0000x reference)
//
#include <hip/hip_runtime.h>

#define FDIM 32
#define NNODES 255
#define NLEAVES 256

__device__ __forceinline__ float fast_sigmoid(float z) {
    // 1/(1+exp(-z)); __expf -> v_exp_f32, rcp -> v_rcp_f32 (approx, ~1 ulp)
    float e = __expf(-z);
    return __builtin_amdgcn_rcpf(1.0f + e);
}

// g for one node: dot(x, W[node]) - c[node], sigmoid. node is wave-uniform ->
// W/c loads should become s_load (scalar cache); x lives in VGPRs.
__device__ __forceinline__ float node_g(const float* __restrict__ W,
                                        const float* __restrict__ c,
                                        const float (&xr)[FDIM], int node) {
    const float* __restrict__ w = W + (node << 5);
    float z0 = -c[node], z1 = 0.f, z2 = 0.f, z3 = 0.f;
#pragma unroll
    for (int k = 0; k < FDIM; k += 4) {
        z0 = fmaf(xr[k + 0], w[k + 0], z0);
        z1 = fmaf(xr[k + 1], w[k + 1], z1);
        z2 = fmaf(xr[k + 2], w[k + 2], z2);
        z3 = fmaf(xr[k + 3], w[k + 3], z3);
    }
    return fast_sigmoid((z0 + z1) + (z2 + z3));
}

// Precompute Wr = relu(feature_importances), c = sum(Wr * sigmoid(feature_splits))
__global__ void dtree_prep(const float* __restrict__ fi, const float* __restrict__ fs,
                           float* __restrict__ W, float* __restrict__ c) {
    int node = threadIdx.x;
    if (node < NNODES) {
        float s = 0.f;
#pragma unroll
        for (int k = 0; k < FDIM; ++k) {
            float w = fi[(node << 5) + k];
            w = w > 0.f ? w : 0.f;
            float sg = fast_sigmoid(fs[(node << 5) + k]);
            W[(node << 5) + k] = w;
            s = fmaf(w, sg, s);
        }
        c[node] = s;
    }
}

__global__ __launch_bounds__(256) void dtree_main(const float* __restrict__ x,
                                                  const float* __restrict__ W,
                                                  const float* __restrict__ c,
                                                  const float* __restrict__ cls,
                                                  float* __restrict__ out) {
    int n = blockIdx.x * blockDim.x + threadIdx.x;

    float xr[FDIM];
    const float4* xp = (const float4*)(x + (size_t)n * FDIM);
#pragma unroll
    for (int q = 0; q < FDIM / 4; ++q) {
        float4 v = xp[q];
        xr[4 * q + 0] = v.x; xr[4 * q + 1] = v.y;
        xr[4 * q + 2] = v.z; xr[4 * q + 3] = v.w;
    }

    float acc = 0.f;
    // level 0 (root) g, computed once
    float g0 = node_g(W, c, xr, 0);
    float g1, g2, g3;          // cached g along current path, levels 1..3
    float p1, p2, p3, p4;      // path probabilities after levels 0..3

    // i = 4-bit prefix of the leaf index (levels 0..3 directions, MSB first).
    // All branches below are wave-uniform (i is uniform) -> no divergence.
    for (int i = 0; i < 16; ++i) {
        if (i == 0) {
            p1 = g0;
            g1 = node_g(W, c, xr, 1);  p2 = p1 * g1;
            g2 = node_g(W, c, xr, 3);  p3 = p2 * g2;
            g3 = node_g(W, c, xr, 7);  p4 = p3 * g3;
        } else {
            int t = __builtin_ctz(i);  // lowest changed bit -> level 3-t flips L->R
            if (t == 0) {
                p4 = p3 * (1.f - g3);
            } else if (t == 1) {
                p3 = p2 * (1.f - g2);
                g3 = node_g(W, c, xr, 7 + (i >> 1)); p4 = p3 * g3;
            } else if (t == 2) {
                p2 = p1 * (1.f - g1);
                g2 = node_g(W, c, xr, 3 + (i >> 2)); p3 = p2 * g2;
                g3 = node_g(W, c, xr, 7 + (i >> 1)); p4 = p3 * g3;
            } else {
                p1 = 1.f - g0;
                g1 = node_g(W, c, xr, 1 + (i >> 3)); p2 = p1 * g1;
                g2 = node_g(W, c, xr, 3 + (i >> 2)); p3 = p2 * g2;
                g3 = node_g(W, c, xr, 7 + (i >> 1)); p4 = p3 * g3;
            }
        }
        // depth-4 subtree under level-4 node (15+i): fully unrolled, static regs
        float g4 = node_g(W, c, xr, 15 + i);
#pragma unroll
        for (int b4 = 0; b4 < 2; ++b4) {
            float p5 = p4 * (b4 ? (1.f - g4) : g4);
            float g5 = node_g(W, c, xr, 31 + 2 * i + b4);
#pragma unroll
            for (int b5 = 0; b5 < 2; ++b5) {
                float p6 = p5 * (b5 ? (1.f - g5) : g5);
                float g6 = node_g(W, c, xr, 63 + 4 * i + 2 * b4 + b5);
#pragma unroll
                for (int b6 = 0; b6 < 2; ++b6) {
                    float p7 = p6 * (b6 ? (1.f - g6) : g6);
                    float g7 = node_g(W, c, xr, 127 + 8 * i + 4 * b4 + 2 * b5 + b6);
                    int lb = 16 * i + 8 * b4 + 4 * b5 + 2 * b6;
                    float c0 = cls[lb], c1 = cls[lb + 1];
                    // p7 * (g7*c0 + (1-g7)*c1) = p7 * (g7*(c0-c1) + c1)
                    acc = fmaf(p7, fmaf(g7, c0 - c1, c1), acc);
                }
            }
        }
    }
    out[n] = acc;
}

extern "C" void kernel_launch(void* const* d_in, const int* in_sizes, int n_in,
                              void* d_out, int out_size, void* d_ws, size_t ws_size,
                              hipStream_t stream) {
    const float* x   = (const float*)d_in[0];
    const float* fi  = (const float*)d_in[1];
    const float* fs  = (const float*)d_in[2];
    const float* cls = (const float*)d_in[3];

    float* W = (float*)d_ws;              // 255*32 floats
    float* c = W + NNODES * FDIM;         // 255 floats

    int nsamp = in_sizes[0] / FDIM;
    float* out = (float*)d_out;

    hipLaunchKernelGGL(dtree_prep, dim3(1), dim3(256), 0, stream, fi, fs, W, c);
    hipLaunchKernelGGL(dtree_main, dim3(nsamp / 256), dim3(256), 0, stream,
                       x, W, c, cls, out);
}